// Round 1
// baseline (216.398 us; speedup 1.0000x reference)
//
#include <hip/hip_runtime.h>

#define NBLOCK 64

// sin(x) for |x| <~ 200, abs error ~1e-7.
// Cody-Waite pi/2 reduction (2 fmas) + cephes polys on [-pi/4, pi/4].
__device__ __forceinline__ float fast_sinf(float x) {
    float kf = rintf(x * 0.63661977236758134f);   // round(x * 2/pi)
    int   q  = (int)kf;
    // pi/2 = HI + LO;  HI = float(pi/2), LO = pi/2 - HI = -4.3711390e-8
    float r = fmaf(kf, -1.5707963705062866f, x);  // x - k*HI (fma-exact product)
    r = fmaf(kf, 4.3711390001862171e-8f, r);      // - k*LO
    float z = r * r;
    // sin poly
    float s = fmaf(z, fmaf(z, -1.9515295891e-4f, 8.3321608736e-3f), -1.6666654611e-1f);
    float sinr = fmaf(z * r, s, r);
    // cos poly
    float c = fmaf(z, fmaf(z, 2.4433157118e-5f, -1.3887316255e-3f), 4.1666645683e-2f);
    float cosr = fmaf(z, fmaf(z, c, -0.5f), 1.0f);
    float res = (q & 1) ? cosr : sinr;
    return (q & 2) ? -res : res;
}

// Exact floored fmod vs float32(2*pi), bit-matching numpy fp32 semantics.
// For x in [0, ~200]: k <= 32, so fmaf(-k, Y, x) is exactly representable
// (result is a multiple of 2^-21 with magnitude < 8 -> <= 24 significand bits).
__device__ __forceinline__ float mod_two_pi(float x) {
    const float Y = 6.2831853071795864769f;       // rounds to float32 2*pi
    float kf = floorf(__fdiv_rn(x, Y));
    float m = fmaf(-kf, Y, x);
    if (m < 0.0f)  { kf -= 1.0f; m = fmaf(-kf, Y, x); }
    if (m >= Y)    { kf += 1.0f; m = fmaf(-kf, Y, x); }
    return m;
}

__global__ __launch_bounds__(256)
void fm_synth_kernel(const float* __restrict__ fm_params,
                     const float* __restrict__ f0_hz,
                     const float* __restrict__ phase_state,
                     float* __restrict__ out, int nv)
{
    int b = blockIdx.x * 256 + threadIdx.x;
    if (b >= nv) return;

    // ---- loads -----------------------------------------------------------
    const float2* fm2 = (const float2*)fm_params;   // 6 floats/voice, 8B aligned
    float2 p01 = fm2[b * 3 + 0];
    float2 p23 = fm2[b * 3 + 1];
    float2 p45 = fm2[b * 3 + 2];
    float  f0  = fmaxf(f0_hz[b], 1.0f);
    float4 st  = ((const float4*)phase_state)[b];

    // ---- params — exact fp32 op order matching the reference -------------
    const float TWO_PI = 6.2831853071795864769f;    // float32: 6.2831855f
    float r1  = __fadd_rn(0.25f, __fmul_rn(p01.y, 15.75f));
    float fb1 = __fmul_rn(p23.x, 0.95f);
    float d2  = __fmul_rn(p23.y, 10.0f);
    float r2  = __fadd_rn(0.25f, __fmul_rn(p45.x, 15.75f));
    float fb2 = __fmul_rn(p45.y, 0.95f);
    float inc1 = __fdiv_rn(__fmul_rn(__fmul_rn(TWO_PI, f0), r1), 16000.0f);
    float inc2 = __fdiv_rn(__fmul_rn(__fmul_rn(TWO_PI, f0), r2), 16000.0f);

    float start1 = st.x, start2 = st.y;
    float l1 = st.z, l2 = st.w;

    // ---- 64-step feedback FM recurrence, samples held in registers -------
    float smp[NBLOCK];
#pragma unroll
    for (int t = 0; t < NBLOCK; ++t) {
        float tf  = (float)t;
        float ph1 = tf * inc1 + start1;
        float ph2 = tf * inc2 + start2;
        float o1 = fast_sinf(ph1 + fb1 * l1);
        float o2 = fast_sinf(ph2 + d2 * o1 + fb2 * l2);
        l1 = o1;
        l2 = o2;
        smp[t] = o2;
    }

    // ---- RMS normalize ----------------------------------------------------
    float ss = 0.0f;
#pragma unroll
    for (int t = 0; t < NBLOCK; ++t) ss = fmaf(smp[t], smp[t], ss);
    float inv = 1.0f / sqrtf(ss * 0.015625f + 1e-5f);   // 1/sqrt(mean + 1e-5)

    // ---- store audio (16 x float4 per voice) ------------------------------
    float4* oa = (float4*)(out + (size_t)b * NBLOCK);
#pragma unroll
    for (int j = 0; j < 16; ++j) {
        float4 v;
        v.x = smp[4 * j + 0] * inv;
        v.y = smp[4 * j + 1] * inv;
        v.z = smp[4 * j + 2] * inv;
        v.w = smp[4 * j + 3] * inv;
        oa[j] = v;
    }

    // ---- phase_end --------------------------------------------------------
    float x1 = __fadd_rn(start1, __fmul_rn(64.0f, inc1));
    float x2 = __fadd_rn(start2, __fmul_rn(64.0f, inc2));
    float4 pe;
    pe.x = mod_two_pi(x1);
    pe.y = mod_two_pi(x2);
    pe.z = l1;
    pe.w = l2;
    ((float4*)(out + (size_t)nv * NBLOCK))[b] = pe;
}

extern "C" void kernel_launch(void* const* d_in, const int* in_sizes, int n_in,
                              void* d_out, int out_size, void* d_ws, size_t ws_size,
                              hipStream_t stream) {
    const float* fm_params   = (const float*)d_in[0];
    const float* f0_hz       = (const float*)d_in[1];
    const float* phase_state = (const float*)d_in[2];
    float* out = (float*)d_out;
    int nv = in_sizes[1];                      // f0_hz has one element per voice
    int grid = (nv + 255) / 256;
    fm_synth_kernel<<<grid, 256, 0, stream>>>(fm_params, f0_hz, phase_state, out, nv);
}

// Round 2
// 171.446 us; speedup vs baseline: 1.2622x; 1.2622x over previous
//
#include <hip/hip_runtime.h>

#define NBLOCK 64

// sin(x) for |x| <~ 200, abs error ~1e-7.
// Cody-Waite pi/2 reduction (2 fmas) + cephes polys on [-pi/4, pi/4].
__device__ __forceinline__ float fast_sinf(float x) {
    float kf = rintf(x * 0.63661977236758134f);   // round(x * 2/pi)
    int   q  = (int)kf;
    // pi/2 = HI + LO;  HI = float(pi/2), LO = pi/2 - HI = -4.3711390e-8
    float r = fmaf(kf, -1.5707963705062866f, x);  // x - k*HI (fma-exact product)
    r = fmaf(kf, 4.3711390001862171e-8f, r);      // - k*LO
    float z = r * r;
    // sin poly
    float s = fmaf(z, fmaf(z, -1.9515295891e-4f, 8.3321608736e-3f), -1.6666654611e-1f);
    float sinr = fmaf(z * r, s, r);
    // cos poly
    float c = fmaf(z, fmaf(z, 2.4433157118e-5f, -1.3887316255e-3f), 4.1666645683e-2f);
    float cosr = fmaf(z, fmaf(z, c, -0.5f), 1.0f);
    float res = (q & 1) ? cosr : sinr;
    return (q & 2) ? -res : res;
}

// Exact floored fmod vs float32(2*pi), bit-matching numpy fp32 semantics.
__device__ __forceinline__ float mod_two_pi(float x) {
    const float Y = 6.2831853071795864769f;       // rounds to float32 2*pi
    float kf = floorf(__fdiv_rn(x, Y));
    float m = fmaf(-kf, Y, x);
    if (m < 0.0f)  { kf -= 1.0f; m = fmaf(-kf, Y, x); }
    if (m >= Y)    { kf += 1.0f; m = fmaf(-kf, Y, x); }
    return m;
}

__global__ __launch_bounds__(256)
void fm_synth_kernel(const float* __restrict__ fm_params,
                     const float* __restrict__ f0_hz,
                     const float* __restrict__ phase_state,
                     float* __restrict__ out, int nv)
{
    // +1-float pad per 16-float slot: conflict-free LDS writes (stride 17 is odd),
    // ~2-way reads (free). 256*17*4 = 17.4 KB -> LDS never the occupancy limit.
    __shared__ float lds[256 * 17];

    int tid = threadIdx.x;
    int b   = blockIdx.x * 256 + tid;
    int bc  = min(b, nv - 1);          // clamped compute index (grid may overshoot)
    bool live = (b < nv);

    // ---- loads -----------------------------------------------------------
    const float2* fm2 = (const float2*)fm_params;   // 6 floats/voice, 8B aligned
    float2 p01 = fm2[bc * 3 + 0];
    float2 p23 = fm2[bc * 3 + 1];
    float2 p45 = fm2[bc * 3 + 2];
    float  f0  = fmaxf(f0_hz[bc], 1.0f);
    float4 st  = ((const float4*)phase_state)[bc];

    // ---- params — exact fp32 op order matching the reference -------------
    const float TWO_PI = 6.2831853071795864769f;
    float r1  = __fadd_rn(0.25f, __fmul_rn(p01.y, 15.75f));
    float fb1 = __fmul_rn(p23.x, 0.95f);
    float d2  = __fmul_rn(p23.y, 10.0f);
    float r2  = __fadd_rn(0.25f, __fmul_rn(p45.x, 15.75f));
    float fb2 = __fmul_rn(p45.y, 0.95f);
    float inc1 = __fdiv_rn(__fmul_rn(__fmul_rn(TWO_PI, f0), r1), 16000.0f);
    float inc2 = __fdiv_rn(__fmul_rn(__fmul_rn(TWO_PI, f0), r2), 16000.0f);

    float start1 = st.x, start2 = st.y;
    float l1 = st.z, l2 = st.w;

    // ---- 64-step feedback FM recurrence, samples held in registers -------
    float smp[NBLOCK];
#pragma unroll
    for (int t = 0; t < NBLOCK; ++t) {
        float tf  = (float)t;
        float ph1 = tf * inc1 + start1;
        float ph2 = tf * inc2 + start2;
        float o1 = fast_sinf(ph1 + fb1 * l1);
        float o2 = fast_sinf(ph2 + d2 * o1 + fb2 * l2);
        l1 = o1;
        l2 = o2;
        smp[t] = o2;
    }

    // ---- RMS normalize ----------------------------------------------------
    float ss = 0.0f;
#pragma unroll
    for (int t = 0; t < NBLOCK; ++t) ss = fmaf(smp[t], smp[t], ss);
    float inv = 1.0f / sqrtf(ss * 0.015625f + 1e-5f);
#pragma unroll
    for (int t = 0; t < NBLOCK; ++t) smp[t] *= inv;

    // ---- audio store via LDS transpose: full-cache-line wave stores -------
    // 4 passes x 16 samples. Read mapping: lane -> (v = tid>>2 (+64k), u = tid&3);
    // each wave-store covers 16 full 64B lines (voice-quad u of 4 voices/quad-group).
    float4* out4 = (float4*)out;
    int blockBase = blockIdx.x * 256;
    int u  = tid & 3;
    int v0 = tid >> 2;
#pragma unroll
    for (int c = 0; c < 4; ++c) {
        __syncthreads();               // WAR guard vs previous pass's reads
        float* slot = &lds[tid * 17];
#pragma unroll
        for (int i = 0; i < 16; ++i) slot[i] = smp[c * 16 + i];
        __syncthreads();
#pragma unroll
        for (int k = 0; k < 4; ++k) {
            int v = v0 + 64 * k;
            const float* src = &lds[v * 17 + u * 4];
            float4 val;
            val.x = src[0]; val.y = src[1]; val.z = src[2]; val.w = src[3];
            if (blockBase + v < nv)
                out4[(size_t)(blockBase + v) * 16 + 4 * c + u] = val;
        }
    }

    // ---- phase_end (already coalesced: one float4 per thread) -------------
    float x1 = __fadd_rn(start1, __fmul_rn(64.0f, inc1));
    float x2 = __fadd_rn(start2, __fmul_rn(64.0f, inc2));
    float4 pe;
    pe.x = mod_two_pi(x1);
    pe.y = mod_two_pi(x2);
    pe.z = l1;
    pe.w = l2;
    if (live)
        ((float4*)(out + (size_t)nv * NBLOCK))[b] = pe;
}

extern "C" void kernel_launch(void* const* d_in, const int* in_sizes, int n_in,
                              void* d_out, int out_size, void* d_ws, size_t ws_size,
                              hipStream_t stream) {
    const float* fm_params   = (const float*)d_in[0];
    const float* f0_hz       = (const float*)d_in[1];
    const float* phase_state = (const float*)d_in[2];
    float* out = (float*)d_out;
    int nv = in_sizes[1];                      // f0_hz has one element per voice
    int grid = (nv + 255) / 256;
    fm_synth_kernel<<<grid, 256, 0, stream>>>(fm_params, f0_hz, phase_state, out, nv);
}